// Round 5
// baseline (40.881 us; speedup 1.0000x reference)
//
#include <hip/hip_runtime.h>

typedef unsigned int uint;

// Problem constants (from setup_inputs)
#define B_     2
#define C_     16
#define H_     66
#define W_     66
#define O_     64
#define CKK    144
#define NCH    36          // CKK/4
#define DIM    64          // output spatial
#define L_     4096        // DIM*DIM
#define N_     8192        // B_*L_
#define PLANE  524288      // N_*O_  (stride between (c,s) planes of rand_idx)
#define TSTRIDE 1024       // padded table row stride (pow2: no mul in addr)
#define TROWS  61          // rows 0..60 (0..7 zeroed: sign(Q)==0 there)
#define TCOLS  1000

typedef _Float16 h4 __attribute__((ext_vector_type(4)));

// ---- prefetch group: 4 chunks, int4 per lane (o-quad, one sign-plane) -----
__device__ __forceinline__ void loadg(int4 (&buf)[4],
                                      const int* __restrict__ rp, int c0) {
#pragma unroll
    for (int j = 0; j < 4; ++j)
        buf[j] = *(const int4*)(rp + (c0 + j) * (2 * PLANE));
}

// ---- consume one group: 4 chunks x 4 o's, sign-specific partial sums ------
__device__ __forceinline__ void procg(const int4 (&buf)[4],
                                      const uint*  __restrict__ xqp,  // &s_xq[t][nloc*NCH]
                                      const uint4* __restrict__ swp,  // &s_wq[sg*16+quad]
                                      const _Float16* __restrict__ tbl,
                                      int c0, float (&sum)[4]) {
#pragma unroll
    for (int j = 0; j < 4; ++j) {
        int c = c0 + j;
        uint  xv = xqp[c];                  // 2 addrs/wave: broadcast, free
        uint4 m  = swp[c * 32];             // ds_read_b128, 512B/wave
        int4  ix = buf[j];
        uint r0 = ((xv & m.x) * 0x01010101u) >> 24;   // byte-sum = dot4
        uint r1 = ((xv & m.y) * 0x01010101u) >> 24;
        uint r2 = ((xv & m.z) * 0x01010101u) >> 24;
        uint r3 = ((xv & m.w) * 0x01010101u) >> 24;
        sum[0] += (float)tbl[(r0 << 10) + ix.x];
        sum[1] += (float)tbl[(r1 << 10) + ix.y];
        sum[2] += (float)tbl[(r2 << 10) + ix.z];
        sum[3] += (float)tbl[(r3 << 10) + ix.w];
    }
}

__launch_bounds__(1024)
__global__ void k_fused(const float* __restrict__ x,
                        const float* __restrict__ wgt,
                        const float* __restrict__ cbias,
                        const float* __restrict__ pmin,
                        const float* __restrict__ pmax,
                        const float* __restrict__ ptbl,
                        const int*   __restrict__ ridx,
                        float* __restrict__ out) {
    __shared__ __align__(16) _Float16 tbl[TROWS * TSTRIDE]; // 124,928 B
    __shared__ uint4 s_wq[NCH * 2 * 16];                    //  18,432 B [c][sg][quad]
    __shared__ float s_bias[O_];                            //     256 B
    __shared__ uint  s_xq[2][16 * NCH];                     //   4,608 B

    const int tid  = threadIdx.x;
    const int wv   = tid >> 6;
    const int lane = tid & 63;
    const int quad = lane & 15;            // o-quad: o0 = 4*quad
    const int sg   = (lane >> 4) & 1;      // 0: + masks, 1: - masks
    const int nsub = lane >> 5;            // which n of the wave's pair
    const int t    = wv >> 3;              // batch stream 0/1
    const int nloc = 2 * (wv & 7) + nsub;  // 0..15 within tile

    const float mn = pmin[0];
    const float sc = pmax[0] - mn;

    // ---- issue 4-deep int4 index prefetch FIRST (oldest in vmcnt queue) ----
    const int n_g = blockIdx.x * 16 + nloc + t * 4096;
    const int* rp = ridx + sg * PLANE + n_g * O_ + quad * 4;
    int4 A[4], Bb[4], Cc[4], Dd[4];
    loadg(A,  rp, 0);
    loadg(Bb, rp, 4);
    loadg(Cc, rp, 8);
    loadg(Dd, rp, 12);

    // ---- Phase 0a: zero whole table region (incl. rows 0..7 and row pads) --
    {
        uint4 z; z.x = z.y = z.z = z.w = 0u;
        uint4* zp = (uint4*)tbl;
        for (int q = tid; q < (TROWS * TSTRIDE) / 8; q += 1024) zp[q] = z;
    }
    __syncthreads();
    // ---- Phase 0b: rows 8..60 -> fp16 LDS at stride 1024 ----
    for (int q = tid; q < 53 * 250; q += 1024) {            // 250 float4 per row
        int r = q / 250, k = q - r * 250;
        float4 v = *(const float4*)(ptbl + (8 + r) * TCOLS + k * 4);
        h4 hh = { (_Float16)v.x, (_Float16)v.y, (_Float16)v.z, (_Float16)v.w };
        *(h4*)(tbl + (8 + r) * TSTRIDE + k * 4) = hh;
    }
    // ---- Phase 0c: ternary weight masks [c][sg][quad] as uint4 ----
    for (int q = tid; q < NCH * 32; q += 1024) {
        int c = q >> 5, r = q & 31;
        int sgg = r >> 4, qd = r & 15;
        uint4 mo;
        uint mk[4];
#pragma unroll
        for (int j = 0; j < 4; ++j) {
            float4 v = *(const float4*)(wgt + (4 * qd + j) * CKK + c * 4);
            uint pm = 0, nm = 0;
            if (v.x > 0.0f) pm |= 0x000000FFu; else if (v.x < 0.0f) nm |= 0x000000FFu;
            if (v.y > 0.0f) pm |= 0x0000FF00u; else if (v.y < 0.0f) nm |= 0x0000FF00u;
            if (v.z > 0.0f) pm |= 0x00FF0000u; else if (v.z < 0.0f) nm |= 0x00FF0000u;
            if (v.w > 0.0f) pm |= 0xFF000000u; else if (v.w < 0.0f) nm |= 0xFF000000u;
            mk[j] = sgg ? nm : pm;
        }
        mo.x = mk[0]; mo.y = mk[1]; mo.z = mk[2]; mo.w = mk[3];
        s_wq[(c * 2 + sgg) * 16 + qd] = mo;
    }
    // ---- Phase 0d: quantize both tiles' 32 patches into s_xq ----
    for (int i = tid; i < 2 * 16 * NCH; i += 1024) {
        int tt = i / (16 * NCH);
        int r  = i - tt * (16 * NCH);
        int nl2 = r / NCH;
        int c2  = r - nl2 * NCH;
        int n2  = blockIdx.x * 16 + nl2 + tt * 4096;
        int b2 = n2 >> 12, l2 = n2 & (L_ - 1);
        int h2 = l2 >> 6,  w2 = l2 & (DIM - 1);
        uint packed = 0;
#pragma unroll
        for (int k = 0; k < 4; ++k) {
            int j  = c2 * 4 + k;
            int ci = j / 9;
            int r2 = j - ci * 9;
            int kh = r2 / 3;
            int kw = r2 - kh * 3;
            float v = x[((b2 * C_ + ci) * H_ + (h2 + kh)) * W_ + (w2 + kw)];
            float t2 = (v - mn) / sc * 15.0f;                  // jax f32 op order
            float q = fminf(fmaxf(rintf(t2), 0.0f), 15.0f);
            packed |= ((uint)q) << (8 * k);
        }
        s_xq[tt][r] = packed;
    }
    // ---- Phase 0e: bias directly from wgt (once, L2-hot) ----
    if (tid < O_) {
        int sw = 0;
        for (int j = 0; j < CKK; ++j) {
            float v = wgt[tid * CKK + j];
            sw += (v > 0.0f) - (v < 0.0f);
        }
        s_bias[tid] = mn * (float)sw + cbias[tid];
    }
    __syncthreads();

    // ---- main: 4-deep software pipeline over 9 groups ----
    const uint*  xqp = &s_xq[t][nloc * NCH];
    const uint4* swp = &s_wq[sg * 16 + quad];
    float sum[4] = {0.f, 0.f, 0.f, 0.f};

    procg(A,  xqp, swp, tbl,  0, sum); loadg(A,  rp, 16);
    procg(Bb, xqp, swp, tbl,  4, sum); loadg(Bb, rp, 20);
    procg(Cc, xqp, swp, tbl,  8, sum); loadg(Cc, rp, 24);
    procg(Dd, xqp, swp, tbl, 12, sum); loadg(Dd, rp, 28);
    procg(A,  xqp, swp, tbl, 16, sum); loadg(A,  rp, 32);
    procg(Bb, xqp, swp, tbl, 20, sum);
    procg(Cc, xqp, swp, tbl, 24, sum);
    procg(Dd, xqp, swp, tbl, 28, sum);
    procg(A,  xqp, swp, tbl, 32, sum);

    // ---- combine +/- halves: partner lane is lane^16 ----
    float f0 = sum[0] - __shfl_xor(sum[0], 16, 64);
    float f1 = sum[1] - __shfl_xor(sum[1], 16, 64);
    float f2 = sum[2] - __shfl_xor(sum[2], 16, 64);
    float f3 = sum[3] - __shfl_xor(sum[3], 16, 64);

    if (sg == 0) {
        const int l  = blockIdx.x * 16 + nloc;
        const int o0 = 4 * quad;
        float4 bv = *(const float4*)(s_bias + o0);
        out[(t * O_ + o0 + 0) * L_ + l] = f0 * sc + bv.x;
        out[(t * O_ + o0 + 1) * L_ + l] = f1 * sc + bv.y;
        out[(t * O_ + o0 + 2) * L_ + l] = f2 * sc + bv.z;
        out[(t * O_ + o0 + 3) * L_ + l] = f3 * sc + bv.w;
    }
}

extern "C" void kernel_launch(void* const* d_in, const int* in_sizes, int n_in,
                              void* d_out, int out_size, void* d_ws, size_t ws_size,
                              hipStream_t stream) {
    const float* x     = (const float*)d_in[0];
    const float* wgt   = (const float*)d_in[1];
    const float* cbias = (const float*)d_in[2];
    const float* pmin  = (const float*)d_in[3];
    const float* pmax  = (const float*)d_in[4];
    const float* ptbl  = (const float*)d_in[5];
    const int*   ridx  = (const int*)d_in[6];
    float* out = (float*)d_out;

    k_fused<<<256, 1024, 0, stream>>>(x, wgt, cbias, pmin, pmax, ptbl, ridx, out);
}